// Round 4
// 731.174 us; speedup vs baseline: 1.0184x; 1.0184x over previous
//
#include <hip/hip_runtime.h>
#include <hip/hip_bf16.h>

#define LN_EPS 1e-5f

typedef __attribute__((ext_vector_type(8))) short short8;   // 8 bf16
typedef __attribute__((ext_vector_type(4))) float f32x4;    // MFMA C/D frag

__device__ __forceinline__ ushort f2bf(float f) {
    __hip_bfloat16 h = __float2bfloat16(f);
    return *reinterpret_cast<ushort*>(&h);
}
__device__ __forceinline__ float bf2f(ushort u) {
    union { float f; unsigned int i; } c; c.i = ((unsigned int)u) << 16; return c.f;
}

// ---------------- init: slots0 = mu + exp(logsigma)*slots_init; zero LN0 sums --------
__global__ void kinit(const float* __restrict__ slots_init, const float* __restrict__ mu,
                      const float* __restrict__ logsig, float* __restrict__ slots,
                      float* __restrict__ sums) {
    int i = blockIdx.x * 256 + threadIdx.x;    // 262144 exactly
    int d = i & 255;
    slots[i] = mu[d] + __expf(logsig[d]) * slots_init[i];
    if (blockIdx.x == 0 && threadIdx.x < 128) sums[threadIdx.x] = 0.f;
}

// ---------------- tiled 64x64 transposes -> bf16: qWT, m1WT, m2WT, vWT ---------------
// qWT[d][e]=qW[e][d]; m1WT[d][j]=m1W[j][d]; m2WT[j][d]=m2W[d][j]; vWT[e][d]=vW[d][e]
__global__ void ktrans(const float* __restrict__ qW, const float* __restrict__ m1W,
                       const float* __restrict__ m2W, const float* __restrict__ vW,
                       ushort* __restrict__ qWT, ushort* __restrict__ m1WT,
                       ushort* __restrict__ m2WT, ushort* __restrict__ vWT) {
    __shared__ float tile[64][65];
    int blk = blockIdx.x, t = threadIdx.x;
    const float* src; ushort* dst; int R, C, tr, tc;
    if (blk < 48) {
        int it = blk >> 4, rem = blk & 15;
        R = 256; C = 256; tr = rem >> 2; tc = rem & 3;
        src = qW + it * 65536; dst = qWT + it * 65536;
    } else if (blk < 144) {
        int li = blk - 48; int it = li >> 5, rem = li & 31;
        R = 512; C = 256; tr = rem >> 2; tc = rem & 3;
        src = m1W + it * 131072; dst = m1WT + it * 131072;
    } else if (blk < 240) {
        int li = blk - 144; int it = li >> 5, rem = li & 31;
        R = 256; C = 512; tr = rem >> 3; tc = rem & 7;
        src = m2W + it * 131072; dst = m2WT + it * 131072;
    } else {
        int li = blk - 240; int it = li >> 4, rem = li & 15;
        R = 256; C = 256; tr = rem >> 2; tc = rem & 3;
        src = vW + it * 65536; dst = vWT + it * 65536;
    }
    int col = t & 63, rq = t >> 6;
    #pragma unroll
    for (int r = 0; r < 16; r++) {
        int row = r * 4 + rq;
        tile[row][col] = src[(tr * 64 + row) * C + tc * 64 + col];
    }
    __syncthreads();
    #pragma unroll
    for (int r = 0; r < 16; r++) {
        int row = r * 4 + rq;
        dst[(tc * 64 + row) * R + tr * 64 + col] = f2bf(tile[col][row]);
    }
}

// ---------------- LN0 pass 1: per-batch sum/sumsq over N*DIN = 1M elems -------------
__global__ void l0a(const float* __restrict__ inp, float* __restrict__ sums) {
    int b = blockIdx.x >> 5, seg = blockIdx.x & 31;
    const float4* p = (const float4*)inp + (size_t)b * 262144 + seg * 8192 + threadIdx.x;
    float s = 0.f, sq = 0.f;
    #pragma unroll
    for (int k = 0; k < 32; k++) {
        float4 v = p[k * 256];
        s  += v.x + v.y + v.z + v.w;
        sq += v.x * v.x + v.y * v.y + v.z * v.z + v.w * v.w;
    }
    __shared__ float r1[256], r2[256];
    r1[threadIdx.x] = s; r2[threadIdx.x] = sq; __syncthreads();
    for (int st = 128; st > 0; st >>= 1) {
        if (threadIdx.x < st) { r1[threadIdx.x] += r1[threadIdx.x + st]; r2[threadIdx.x] += r2[threadIdx.x + st]; }
        __syncthreads();
    }
    if (threadIdx.x == 0) { atomicAdd(&sums[b], r1[0]); atomicAdd(&sums[64 + b], r2[0]); }
}

// ---------------- LN0 pass 2: normalize + write bf16 x in MFMA-frag order ------------
// xgs[tile16(16384)][ds(8)][lane(64)][j(8)]: x[tile16*16+(lane&15)][ds*32+(lane>>4)*8+j]
// One wave owns (ntile, ds, batch-half) and loops 32 batches: ln0w/ln0b read ONCE.
__global__ void l0bs(const float* __restrict__ inp, const float* __restrict__ ln0w,
                     const float* __restrict__ ln0b, const float* __restrict__ sums,
                     ushort* __restrict__ xgs) {
    int gw = blockIdx.x * 4 + (threadIdx.x >> 6);     // 4096 wave tasks
    int lane = threadIdx.x & 63, l15 = lane & 15, quad = lane >> 4;
    int ntile = gw >> 4;                              // 0..255 (within-batch 16-token tile)
    int ds = (gw >> 1) & 7;
    int b0 = (gw & 1) * 32;
    int n = ntile * 16 + l15;                         // within-batch token
    int dcol = ds * 32 + quad * 8;
    const float4* wp = (const float4*)(ln0w + n * 256 + dcol);
    const float4* bp = (const float4*)(ln0b + n * 256 + dcol);
    float4 w0 = wp[0], w1 = wp[1];
    float4 c0 = bp[0], c1 = bp[1];
    #pragma unroll 4
    for (int bi = 0; bi < 32; bi++) {
        int b = b0 + bi;
        float mean = sums[b] * (1.f / 1048576.f);
        float rstd = rsqrtf(sums[64 + b] * (1.f / 1048576.f) - mean * mean + LN_EPS);
        const float4* xp = (const float4*)(inp + (size_t)b * 1048576 + n * 256 + dcol);
        float4 v0 = xp[0], v1 = xp[1];
        ushort o[8];
        o[0] = f2bf((v0.x - mean) * rstd * w0.x + c0.x);
        o[1] = f2bf((v0.y - mean) * rstd * w0.y + c0.y);
        o[2] = f2bf((v0.z - mean) * rstd * w0.z + c0.z);
        o[3] = f2bf((v0.w - mean) * rstd * w0.w + c0.w);
        o[4] = f2bf((v1.x - mean) * rstd * w1.x + c1.x);
        o[5] = f2bf((v1.y - mean) * rstd * w1.y + c1.y);
        o[6] = f2bf((v1.z - mean) * rstd * w1.z + c1.z);
        o[7] = f2bf((v1.w - mean) * rstd * w1.w + c1.w);
        *(short8*)(xgs + ((size_t)((b * 256 + ntile) * 8 + ds) * 64 + lane) * 8) = *(short8*)o;
    }
}

// ---------------- per-iter: LN1(slots) -> q' = (q+qb)/16 -> qk = q'@kW (bf16 frags) --
// Also qkb[s] = q'.kb, denom = 0.  grid 64 (one block per batch).
__global__ void kq(const float* __restrict__ slots, const float* __restrict__ ln1w,
                   const float* __restrict__ ln1b, const ushort* __restrict__ qWT,
                   const float* __restrict__ qb, const float* __restrict__ kW,
                   const float* __restrict__ kb,
                   ushort* __restrict__ qkf, float* __restrict__ qkb,
                   float* __restrict__ denom) {
    int b = blockIdx.x, t = threadIdx.x;
    __shared__ float sl[4096];
    __shared__ float qs[4096];
    __shared__ float r1[256], r2[256];
    const float* sp = slots + b * 4096;
    float vals[16]; float s = 0.f, sq = 0.f;
    #pragma unroll
    for (int k = 0; k < 16; k++) { float v = sp[k * 256 + t]; vals[k] = v; s += v; sq += v * v; }
    r1[t] = s; r2[t] = sq; __syncthreads();
    for (int st = 128; st > 0; st >>= 1) {
        if (t < st) { r1[t] += r1[t + st]; r2[t] += r2[t + st]; }
        __syncthreads();
    }
    float m  = r1[0] * (1.f / 4096.f);
    float rs = rsqrtf(r2[0] * (1.f / 4096.f) - m * m + LN_EPS);
    #pragma unroll
    for (int k = 0; k < 16; k++)
        sl[k * 256 + t] = (vals[k] - m) * rs * ln1w[k * 256 + t] + ln1b[k * 256 + t];
    __syncthreads();
    // q'[s, e=t] = (sum_d sl[s,d]*qW[e,d] + qb[e]) / 16
    {
        float acc[16];
        #pragma unroll
        for (int k = 0; k < 16; k++) acc[k] = 0.f;
        for (int d = 0; d < 256; d++) {
            float wv = bf2f(qWT[d * 256 + t]);
            #pragma unroll
            for (int k = 0; k < 16; k++) acc[k] += sl[k * 256 + d] * wv;
        }
        float qbv = qb[t];
        #pragma unroll
        for (int k = 0; k < 16; k++) qs[k * 256 + t] = (acc[k] + qbv) * (1.f / 16.f);
    }
    __syncthreads();
    // qk[s, d=t] = sum_e q'[s,e]*kW[e,d]  -> bf16 A-frag layout
    {
        float acc[16];
        #pragma unroll
        for (int k = 0; k < 16; k++) acc[k] = 0.f;
        for (int e = 0; e < 256; e++) {
            float wv = kW[e * 256 + t];
            #pragma unroll
            for (int k = 0; k < 16; k++) acc[k] += qs[k * 256 + e] * wv;
        }
        int d = t;
        int ds = d >> 5, quad = (d >> 3) & 3, j = d & 7;
        #pragma unroll
        for (int k = 0; k < 16; k++)
            qkf[(size_t)(b * 8 + ds) * 512 + (k + 16 * quad) * 8 + j] = f2bf(acc[k]);
    }
    if (t < 16) {
        float kbs = 0.f;
        for (int e = 0; e < 256; e++) kbs += qs[t * 256 + e] * kb[e];
        qkb[b * 16 + t] = kbs;
    } else if (t < 32) {
        denom[b * 16 + (t - 16)] = 0.f;
    }
}

// ---------------- THE hot kernel: dist = qk@x^T (+qkb) -> softmax -> ax = attn@x -----
// grid = B*16; block = 256 tokens as 4 sub-tiles of 64; 4 waves; xgs streamed once.
// (katt reverted to the proven scalar-gather ax path; denom now in-register.)
__launch_bounds__(256, 4)
__global__ void katt(const ushort* __restrict__ xgs, const ushort* __restrict__ qkf,
                     const float* __restrict__ qkb, float* __restrict__ denom,
                     float* __restrict__ partials) {
    int b = blockIdx.x >> 4, chunk = blockIdx.x & 15;
    int tid = threadIdx.x;
    int lane = tid & 63, w = tid >> 6;
    int l15 = lane & 15, quad = lane >> 4;

    __shared__ ushort xt[64 * 268];     // sub-tile x [n_local][d], pitch 268 (34.3 KB)
    __shared__ ushort attn[16 * 72];    // attn [s][n_local], pitch 72

    // qk A-frags: invariant across the whole block (one batch)
    short8 qkfr[8];
    #pragma unroll
    for (int ds = 0; ds < 8; ds++)
        qkfr[ds] = *(const short8*)(qkf + ((size_t)(b * 8 + ds) * 512 + lane * 8));
    float4 qo = *(const float4*)(qkb + b * 16 + quad * 4);

    f32x4 pacc[4];
    #pragma unroll
    for (int u = 0; u < 4; u++) pacc[u] = f32x4{0.f, 0.f, 0.f, 0.f};
    float dp0 = 0.f, dp1 = 0.f, dp2 = 0.f, dp3 = 0.f;   // per-lane denom partials

    int tile0 = b * 256 + chunk * 16;   // global 16-token tile base

    // prefetch sub 0 into regs (wave w stages token-tile w, all 8 d-slices)
    short8 pf[8];
    #pragma unroll
    for (int i = 0; i < 8; i++)
        pf[i] = *(const short8*)(xgs + (((size_t)(tile0 + w) * 8 + i) * 64 + lane) * 8);

    #pragma unroll 1
    for (int sub = 0; sub < 4; sub++) {
        __syncthreads();                // prior ax done reading xt
        #pragma unroll
        for (int i = 0; i < 8; i++)
            *(short8*)(&xt[(w * 16 + l15) * 268 + i * 32 + quad * 8]) = pf[i];
        __syncthreads();
        if (sub < 3) {                  // prefetch next sub while computing
            #pragma unroll
            for (int i = 0; i < 8; i++)
                pf[i] = *(const short8*)(xgs + (((size_t)(tile0 + (sub + 1) * 4 + w) * 8 + i) * 64 + lane) * 8);
        }
        // ===== dist tile [16s x 16n], wave w owns n_local [w*16, w*16+16) =====
        f32x4 dc = f32x4{0.f, 0.f, 0.f, 0.f};
        #pragma unroll
        for (int ds = 0; ds < 8; ds++) {
            short8 bk = *(const short8*)(&xt[(w * 16 + l15) * 268 + ds * 32 + quad * 8]);
            dc = __builtin_amdgcn_mfma_f32_16x16x32_bf16(qkfr[ds], bk, dc, 0, 0, 0);
        }
        dc[0] += qo.x; dc[1] += qo.y; dc[2] += qo.z; dc[3] += qo.w;
        // softmax over the 16 slots (4 regs x 4 quads; n fixed per lane)
        float mx = fmaxf(fmaxf(dc[0], dc[1]), fmaxf(dc[2], dc[3]));
        mx = fmaxf(mx, __shfl_xor(mx, 16));
        mx = fmaxf(mx, __shfl_xor(mx, 32));
        float e0 = __expf(dc[0] - mx), e1 = __expf(dc[1] - mx);
        float e2 = __expf(dc[2] - mx), e3 = __expf(dc[3] - mx);
        float lsum = e0 + e1 + e2 + e3;
        lsum += __shfl_xor(lsum, 16); lsum += __shfl_xor(lsum, 32);
        float inv = 1.f / lsum;
        float p0 = e0 * inv, p1 = e1 * inv, p2 = e2 * inv, p3 = e3 * inv;
        dp0 += p0; dp1 += p1; dp2 += p2; dp3 += p3;     // denom partials in-register
        attn[(quad * 4 + 0) * 72 + w * 16 + l15] = f2bf(p0);
        attn[(quad * 4 + 1) * 72 + w * 16 + l15] = f2bf(p1);
        attn[(quad * 4 + 2) * 72 + w * 16 + l15] = f2bf(p2);
        attn[(quad * 4 + 3) * 72 + w * 16 + l15] = f2bf(p3);
        __syncthreads();                // attn visible to all waves

        // ===== ax: pacc[s][d] += sum_n attn[s,n]*x[n,d]; wave w owns d [w*64,(w+1)*64) =====
        #pragma unroll
        for (int ns = 0; ns < 2; ns++) {
            short8 aa = *(const short8*)(&attn[l15 * 72 + ns * 32 + quad * 8]);
            #pragma unroll
            for (int u = 0; u < 4; u++) {
                ushort tmp[8];
                #pragma unroll
                for (int j = 0; j < 8; j++)
                    tmp[j] = xt[(ns * 32 + quad * 8 + j) * 268 + (w * 4 + u) * 16 + l15];
                pacc[u] = __builtin_amdgcn_mfma_f32_16x16x32_bf16(aa, *(short8*)tmp, pacc[u], 0, 0, 0);
            }
        }
    }

    // denom: reduce per-lane partials over the 16 n-lanes of this wave, then atomics.
    // Lanes sharing 'quad' differ exactly in bits 0..3 -> xor masks 1,2,4,8.
    #pragma unroll
    for (int m = 1; m < 16; m <<= 1) {
        dp0 += __shfl_xor(dp0, m); dp1 += __shfl_xor(dp1, m);
        dp2 += __shfl_xor(dp2, m); dp3 += __shfl_xor(dp3, m);
    }
    if (l15 == 0) {
        atomicAdd(&denom[b * 16 + quad * 4 + 0], dp0);
        atomicAdd(&denom[b * 16 + quad * 4 + 1], dp1);
        atomicAdd(&denom[b * 16 + quad * 4 + 2], dp2);
        atomicAdd(&denom[b * 16 + quad * 4 + 3], dp3);
    }

    float* pout = partials + (size_t)(b * 16 + chunk) * 4096;   // [s][d]
    #pragma unroll
    for (int u = 0; u < 4; u++)
        #pragma unroll
        for (int r = 0; r < 4; r++)
            pout[(quad * 4 + r) * 256 + (w * 4 + u) * 16 + l15] = pacc[u][r];
}

// ---------------- reduce chunks + apply vW^T + vb, divide by denom -------------------
// grid 256 = (b, d-quarter)
__global__ void kred2(const float* __restrict__ partials, const float* __restrict__ denom,
                      const ushort* __restrict__ vWT, const float* __restrict__ vb,
                      float* __restrict__ slots) {
    int b = blockIdx.x >> 2, dq = blockIdx.x & 3, t = threadIdx.x;
    __shared__ float axs[4096];
    __shared__ float dn[16];
    #pragma unroll
    for (int i = 0; i < 16; i++) {
        int idx = i * 256 + t;
        float ssum = 0.f;
        #pragma unroll
        for (int c = 0; c < 16; c++) ssum += partials[(size_t)b * 65536 + c * 4096 + idx];
        axs[idx] = ssum;
    }
    if (t < 16) dn[t] = denom[b * 16 + t];
    __syncthreads();
    int d = dq * 64 + (t & 63), sg = t >> 6;
    float acc[4];
    #pragma unroll
    for (int i = 0; i < 4; i++) acc[i] = 0.f;
    for (int e = 0; e < 256; e++) {
        float wv = bf2f(vWT[e * 256 + d]);
        #pragma unroll
        for (int i = 0; i < 4; i++) acc[i] += axs[(sg + i * 4) * 256 + e] * wv;
    }
    float vbd = vb[d];
    #pragma unroll
    for (int i = 0; i < 4; i++) {
        int s = sg + i * 4;
        float A = dn[s];
        slots[b * 4096 + s * 256 + d] = (acc[i] + vbd * A) / (A + 1e-7f);
    }
}

// ---------------- LN2 + MLP layer 1 (relu) -> htmp bf16; grid 256 = (b, h-quarter) ---
__global__ void kfin1(const float* __restrict__ slots_in, const float* __restrict__ ln2w,
                      const float* __restrict__ ln2b, const ushort* __restrict__ m1WT,
                      const float* __restrict__ m1b, ushort* __restrict__ htmp) {
    int b = blockIdx.x >> 2, hq = blockIdx.x & 3, t = threadIdx.x;
    __shared__ float s2[4096];
    __shared__ float r1[256], r2[256];
    const float* sp = slots_in + b * 4096;
    float vals[16]; float s = 0.f, sq = 0.f;
    #pragma unroll
    for (int k = 0; k < 16; k++) { float v = sp[k * 256 + t]; vals[k] = v; s += v; sq += v * v; }
    r1[t] = s; r2[t] = sq; __syncthreads();
    for (int st = 128; st > 0; st >>= 1) {
        if (t < st) { r1[t] += r1[t + st]; r2[t] += r2[t + st]; }
        __syncthreads();
    }
    float m  = r1[0] * (1.f / 4096.f);
    float rs = rsqrtf(r2[0] * (1.f / 4096.f) - m * m + LN_EPS);
    #pragma unroll
    for (int k = 0; k < 16; k++)
        s2[k * 256 + t] = (vals[k] - m) * rs * ln2w[k * 256 + t] + ln2b[k * 256 + t];
    __syncthreads();
    int j = hq * 128 + (t & 127), sg2 = t >> 7;   // s in {sg2, sg2+2, ..., sg2+14}
    float acc[8];
    #pragma unroll
    for (int i = 0; i < 8; i++) acc[i] = 0.f;
    for (int d = 0; d < 256; d++) {
        float wv = bf2f(m1WT[d * 512 + j]);
        #pragma unroll
        for (int i = 0; i < 8; i++) acc[i] += s2[(sg2 + i * 2) * 256 + d] * wv;
    }
    float bias = m1b[j];
    #pragma unroll
    for (int i = 0; i < 8; i++)
        htmp[b * 8192 + (sg2 + i * 2) * 512 + j] = f2bf(fmaxf(acc[i] + bias, 0.f));
}

// ---------------- MLP layer 2 + residual; grid 256 = (b, d-quarter) ------------------
__global__ void kfin2(const ushort* __restrict__ htmp, const ushort* __restrict__ m2WT,
                      const float* __restrict__ m2b, float* __restrict__ slots,
                      float* __restrict__ final_out, int write_final) {
    int b = blockIdx.x >> 2, dq = blockIdx.x & 3, t = threadIdx.x;
    __shared__ float hl[8192];
    #pragma unroll
    for (int i = 0; i < 32; i++) {
        int idx = i * 256 + t;
        hl[idx] = bf2f(htmp[b * 8192 + idx]);
    }
    __syncthreads();
    int d = dq * 64 + (t & 63), sg = t >> 6;
    float acc[4];
    #pragma unroll
    for (int i = 0; i < 4; i++) acc[i] = 0.f;
    for (int j = 0; j < 512; j++) {
        float wv = bf2f(m2WT[j * 256 + d]);
        #pragma unroll
        for (int i = 0; i < 4; i++) acc[i] += hl[(sg + i * 4) * 512 + j] * wv;
    }
    float bias2 = m2b[d];
    #pragma unroll
    for (int i = 0; i < 4; i++) {
        int s = sg + i * 4;
        float raw = slots[b * 4096 + s * 256 + d];
        float val = raw + acc[i] + bias2;
        slots[b * 4096 + s * 256 + d] = val;
        if (write_final) final_out[b * 4096 + s * 256 + d] = val;
    }
}

extern "C" void kernel_launch(void* const* d_in, const int* in_sizes, int n_in,
                              void* d_out, int out_size, void* d_ws, size_t ws_size,
                              hipStream_t stream) {
    const float* inputs     = (const float*)d_in[0];
    const float* slots_init = (const float*)d_in[1];
    const float* mu         = (const float*)d_in[2];
    const float* logsig     = (const float*)d_in[3];
    const float* ln0w       = (const float*)d_in[4];
    const float* ln0b       = (const float*)d_in[5];
    const float* ln1w       = (const float*)d_in[6];
    const float* ln1b       = (const float*)d_in[7];
    const float* ln2w       = (const float*)d_in[8];
    const float* ln2b       = (const float*)d_in[9];
    const float* qW         = (const float*)d_in[10];
    const float* qb         = (const float*)d_in[11];
    const float* kW         = (const float*)d_in[12];
    const float* kb         = (const float*)d_in[13];
    const float* vW         = (const float*)d_in[14];
    const float* vb         = (const float*)d_in[15];
    const float* m1W        = (const float*)d_in[16];
    const float* m1b        = (const float*)d_in[17];
    const float* m2W        = (const float*)d_in[18];
    const float* m2b        = (const float*)d_in[19];

    char* ws = (char*)d_ws;
    ushort* xgs     = (ushort*)(ws);                   // 134,217,728 B
    float*  partials= (float*)(ws + 134217728);        //  16,777,216 B
    ushort* qkf     = (ushort*)(ws + 150994944);       //     524,288 B
    ushort* htmp    = (ushort*)(ws + 151519232);       //   1,048,576 B
    float*  slots   = (float*)(ws + 152567808);        //   1,048,576 B
    ushort* qWT     = (ushort*)(ws + 153616384);       //     393,216 B
    ushort* m1WT    = (ushort*)(ws + 154009600);       //     786,432 B
    ushort* m2WT    = (ushort*)(ws + 154796032);       //     786,432 B
    ushort* vWT     = (ushort*)(ws + 155582464);       //     393,216 B
    float*  denom   = (float*)(ws + 155975680);        //       4,096 B
    float*  qkb     = (float*)(ws + 155979776);        //       4,096 B
    float*  sums    = (float*)(ws + 155983872);        //         512 B
    // total 155,984,384 B <= 157,295,104 B proven available in R3

    kinit<<<1024, 256, 0, stream>>>(slots_init, mu, logsig, slots, sums);
    ktrans<<<288, 256, 0, stream>>>(qW, m1W, m2W, vW, qWT, m1WT, m2WT, vWT);
    l0a<<<2048, 256, 0, stream>>>(inputs, sums);
    l0bs<<<1024, 256, 0, stream>>>(inputs, ln0w, ln0b, sums, xgs);

    for (int it = 0; it < 3; it++) {
        kq<<<64, 256, 0, stream>>>(slots, ln1w, ln1b, qWT + it * 65536, qb + it * 256,
                                   kW + it * 65536, kb + it * 256, qkf, qkb, denom);
        katt<<<1024, 256, 0, stream>>>(xgs, qkf, qkb, denom, partials);
        kred2<<<256, 256, 0, stream>>>(partials, denom, vWT + it * 65536, vb + it * 256, slots);
        kfin1<<<256, 256, 0, stream>>>(slots, ln2w, ln2b, m1WT + it * 131072, m1b + it * 512, htmp);
        kfin2<<<256, 256, 0, stream>>>(htmp, m2WT + it * 131072, m2b + it * 256, slots,
                                       (float*)d_out, it == 2 ? 1 : 0);
    }
}

// Round 5
// 578.192 us; speedup vs baseline: 1.2878x; 1.2646x over previous
//
#include <hip/hip_runtime.h>
#include <hip/hip_bf16.h>

#define LN_EPS 1e-5f

typedef __attribute__((ext_vector_type(8))) short short8;   // 8 bf16
typedef __attribute__((ext_vector_type(4))) float f32x4;    // MFMA C/D frag

__device__ __forceinline__ ushort f2bf(float f) {
    __hip_bfloat16 h = __float2bfloat16(f);
    return *reinterpret_cast<ushort*>(&h);
}
__device__ __forceinline__ float bf2f(ushort u) {
    union { float f; unsigned int i; } c; c.i = ((unsigned int)u) << 16; return c.f;
}

// ---------------- init: slots0 = mu + exp(logsigma)*slots_init; zero LN0 sums --------
__global__ void kinit(const float* __restrict__ slots_init, const float* __restrict__ mu,
                      const float* __restrict__ logsig, float* __restrict__ slots,
                      float* __restrict__ sums) {
    int i = blockIdx.x * 256 + threadIdx.x;    // 262144 exactly
    int d = i & 255;
    slots[i] = mu[d] + __expf(logsig[d]) * slots_init[i];
    if (blockIdx.x == 0 && threadIdx.x < 128) sums[threadIdx.x] = 0.f;
}

// ---------------- weight prep --------------------------------------------------------
// blk 0-47   : qWc[e][d] = bf16 cast of qW (NO transpose; MFMA B-frag reads rows)
// blk 48-95  : kWT[d][e] = bf16 transpose of kW
// blk 96-191 : m1WT[d][j] = m1W[j][d]
// blk 192-287: m2WT[j][d] = m2W[d][j]
// blk 288-335: vWT[e][d]  = vW[d][e]
__global__ void ktrans(const float* __restrict__ qW, const float* __restrict__ kW,
                       const float* __restrict__ m1W, const float* __restrict__ m2W,
                       const float* __restrict__ vW,
                       ushort* __restrict__ qWc, ushort* __restrict__ kWT,
                       ushort* __restrict__ m1WT, ushort* __restrict__ m2WT,
                       ushort* __restrict__ vWT) {
    int blk = blockIdx.x, t = threadIdx.x;
    int col = t & 63, rq = t >> 6;
    if (blk < 48) {   // straight cast copy, 64x64 tile
        int it = blk >> 4, rem = blk & 15;
        int tr = rem >> 2, tc = rem & 3;
        const float* src = qW + it * 65536;
        ushort* dst = qWc + it * 65536;
        #pragma unroll
        for (int r = 0; r < 16; r++) {
            int row = r * 4 + rq;
            int idx = (tr * 64 + row) * 256 + tc * 64 + col;
            dst[idx] = f2bf(src[idx]);
        }
        return;
    }
    __shared__ float tile[64][65];
    const float* src; ushort* dst; int R, C, tr, tc;
    if (blk < 96) {
        int li = blk - 48; int it = li >> 4, rem = li & 15;
        R = 256; C = 256; tr = rem >> 2; tc = rem & 3;
        src = kW + it * 65536; dst = kWT + it * 65536;
    } else if (blk < 192) {
        int li = blk - 96; int it = li >> 5, rem = li & 31;
        R = 512; C = 256; tr = rem >> 2; tc = rem & 3;
        src = m1W + it * 131072; dst = m1WT + it * 131072;
    } else if (blk < 288) {
        int li = blk - 192; int it = li >> 5, rem = li & 31;
        R = 256; C = 512; tr = rem >> 3; tc = rem & 7;
        src = m2W + it * 131072; dst = m2WT + it * 131072;
    } else {
        int li = blk - 288; int it = li >> 4, rem = li & 15;
        R = 256; C = 256; tr = rem >> 2; tc = rem & 3;
        src = vW + it * 65536; dst = vWT + it * 65536;
    }
    #pragma unroll
    for (int r = 0; r < 16; r++) {
        int row = r * 4 + rq;
        tile[row][col] = src[(tr * 64 + row) * C + tc * 64 + col];
    }
    __syncthreads();
    #pragma unroll
    for (int r = 0; r < 16; r++) {
        int row = r * 4 + rq;
        dst[(tc * 64 + row) * R + tr * 64 + col] = f2bf(tile[col][row]);
    }
}

// ---------------- LN0 pass 1: per-batch sum/sumsq over N*DIN = 1M elems -------------
__global__ void l0a(const float* __restrict__ inp, float* __restrict__ sums) {
    int b = blockIdx.x >> 5, seg = blockIdx.x & 31;
    const float4* p = (const float4*)inp + (size_t)b * 262144 + seg * 8192 + threadIdx.x;
    float s = 0.f, sq = 0.f;
    #pragma unroll
    for (int k = 0; k < 32; k++) {
        float4 v = p[k * 256];
        s  += v.x + v.y + v.z + v.w;
        sq += v.x * v.x + v.y * v.y + v.z * v.z + v.w * v.w;
    }
    __shared__ float r1[256], r2[256];
    r1[threadIdx.x] = s; r2[threadIdx.x] = sq; __syncthreads();
    for (int st = 128; st > 0; st >>= 1) {
        if (threadIdx.x < st) { r1[threadIdx.x] += r1[threadIdx.x + st]; r2[threadIdx.x] += r2[threadIdx.x + st]; }
        __syncthreads();
    }
    if (threadIdx.x == 0) { atomicAdd(&sums[b], r1[0]); atomicAdd(&sums[64 + b], r2[0]); }
}

// ---------------- LN0 pass 2: normalize + write bf16 x in MFMA-frag order ------------
// xgs[tile16(16384)][ds(8)][lane(64)][j(8)]: x[tile16*16+(lane&15)][ds*32+(lane>>4)*8+j]
__global__ void l0bs(const float* __restrict__ inp, const float* __restrict__ ln0w,
                     const float* __restrict__ ln0b, const float* __restrict__ sums,
                     ushort* __restrict__ xgs) {
    int gw = blockIdx.x * 4 + (threadIdx.x >> 6);     // 4096 wave tasks
    int lane = threadIdx.x & 63, l15 = lane & 15, quad = lane >> 4;
    int ntile = gw >> 4;                              // 0..255 (within-batch 16-token tile)
    int ds = (gw >> 1) & 7;
    int b0 = (gw & 1) * 32;
    int n = ntile * 16 + l15;                         // within-batch token
    int dcol = ds * 32 + quad * 8;
    const float4* wp = (const float4*)(ln0w + n * 256 + dcol);
    const float4* bp = (const float4*)(ln0b + n * 256 + dcol);
    float4 w0 = wp[0], w1 = wp[1];
    float4 c0 = bp[0], c1 = bp[1];
    #pragma unroll 4
    for (int bi = 0; bi < 32; bi++) {
        int b = b0 + bi;
        float mean = sums[b] * (1.f / 1048576.f);
        float rstd = rsqrtf(sums[64 + b] * (1.f / 1048576.f) - mean * mean + LN_EPS);
        const float4* xp = (const float4*)(inp + (size_t)b * 1048576 + n * 256 + dcol);
        float4 v0 = xp[0], v1 = xp[1];
        ushort o[8];
        o[0] = f2bf((v0.x - mean) * rstd * w0.x + c0.x);
        o[1] = f2bf((v0.y - mean) * rstd * w0.y + c0.y);
        o[2] = f2bf((v0.z - mean) * rstd * w0.z + c0.z);
        o[3] = f2bf((v0.w - mean) * rstd * w0.w + c0.w);
        o[4] = f2bf((v1.x - mean) * rstd * w1.x + c1.x);
        o[5] = f2bf((v1.y - mean) * rstd * w1.y + c1.y);
        o[6] = f2bf((v1.z - mean) * rstd * w1.z + c1.z);
        o[7] = f2bf((v1.w - mean) * rstd * w1.w + c1.w);
        *(short8*)(xgs + ((size_t)((b * 256 + ntile) * 8 + ds) * 64 + lane) * 8) = *(short8*)o;
    }
}

// ---------------- per-iter: MFMA version of kq ---------------------------------------
// LN1(slots) -> q' = (sl@qW^T + qb)/16 -> qk = q'@kW, all via 16x16x32 MFMA.
// Frag layouts identical to katt's proven ones:
//   A: row=l15, k=(lane>>4)*8+j (per 32-k group)   B: col=l15, k=(lane>>4)*8+j
//   C: row=(lane>>4)*4+r, col=l15
// grid 64 (one block per batch), 4 waves.
__global__ void kqm(const float* __restrict__ slots, const float* __restrict__ ln1w,
                    const float* __restrict__ ln1b, const ushort* __restrict__ qWc,
                    const float* __restrict__ qb, const ushort* __restrict__ kWT,
                    const float* __restrict__ kb,
                    ushort* __restrict__ qkf, float* __restrict__ qkb,
                    float* __restrict__ denom) {
    int b = blockIdx.x, t = threadIdx.x;
    int lane = t & 63, w = t >> 6, l15 = lane & 15, quad = lane >> 4;
    __shared__ ushort slb[16 * 264];    // bf16 LN1'd slots [s][d], pitch 264 (16B rows)
    __shared__ ushort qsb[16 * 264];    // bf16 q'     [s][e]
    __shared__ ushort qkl[16 * 264];    // bf16 qk     [s][d]
    __shared__ float  qsf[16 * 260];    // f32  q' for qkb
    __shared__ float  r1[256], r2[256];

    // ---- LN1 ----
    const float* sp = slots + b * 4096;
    float vals[16]; float s = 0.f, sq = 0.f;
    #pragma unroll
    for (int k = 0; k < 16; k++) { float v = sp[k * 256 + t]; vals[k] = v; s += v; sq += v * v; }
    r1[t] = s; r2[t] = sq; __syncthreads();
    for (int st = 128; st > 0; st >>= 1) {
        if (t < st) { r1[t] += r1[t + st]; r2[t] += r2[t + st]; }
        __syncthreads();
    }
    float m  = r1[0] * (1.f / 4096.f);
    float rs = rsqrtf(r2[0] * (1.f / 4096.f) - m * m + LN_EPS);
    #pragma unroll
    for (int k = 0; k < 16; k++)
        slb[k * 264 + t] = f2bf((vals[k] - m) * rs * ln1w[k * 256 + t] + ln1b[k * 256 + t]);
    __syncthreads();

    // ---- pass1: q'[s,e] = (sum_d sl[s,d]*qW[e,d] + qb[e]) / 16 ----
    short8 af[8];
    #pragma unroll
    for (int ds = 0; ds < 8; ds++)
        af[ds] = *(const short8*)(&slb[l15 * 264 + ds * 32 + quad * 8]);
    #pragma unroll
    for (int p = 0; p < 4; p++) {
        int et = w * 4 + p;
        f32x4 c = f32x4{0.f, 0.f, 0.f, 0.f};
        #pragma unroll
        for (int ds = 0; ds < 8; ds++) {
            short8 bf_ = *(const short8*)(qWc + (size_t)(et * 16 + l15) * 256 + ds * 32 + quad * 8);
            c = __builtin_amdgcn_mfma_f32_16x16x32_bf16(af[ds], bf_, c, 0, 0, 0);
        }
        float qbv = qb[et * 16 + l15];
        #pragma unroll
        for (int r = 0; r < 4; r++) {
            float val = (c[r] + qbv) * (1.f / 16.f);
            qsf[(quad * 4 + r) * 260 + et * 16 + l15] = val;
            qsb[(quad * 4 + r) * 264 + et * 16 + l15] = f2bf(val);
        }
    }
    __syncthreads();

    // ---- qkb[s] = q'[s,:] . kb  (16 lanes per s, shfl reduce) ----
    {
        int ss = w * 4 + quad;          // s handled by this 16-lane group
        float pp = 0.f;
        #pragma unroll
        for (int e = 0; e < 16; e++) pp += qsf[ss * 260 + l15 * 16 + e] * kb[l15 * 16 + e];
        pp += __shfl_xor(pp, 1); pp += __shfl_xor(pp, 2);
        pp += __shfl_xor(pp, 4); pp += __shfl_xor(pp, 8);
        if (l15 == 0) qkb[b * 16 + ss] = pp;
    }
    if (t < 16) denom[b * 16 + t] = 0.f;

    // ---- pass2: qk[s,d] = sum_e q'[s,e]*kW[e,d]  (B from kWT[d][e]) ----
    short8 af2[8];
    #pragma unroll
    for (int es = 0; es < 8; es++)
        af2[es] = *(const short8*)(&qsb[l15 * 264 + es * 32 + quad * 8]);
    #pragma unroll
    for (int p = 0; p < 4; p++) {
        int dt = w * 4 + p;
        f32x4 c2 = f32x4{0.f, 0.f, 0.f, 0.f};
        #pragma unroll
        for (int es = 0; es < 8; es++) {
            short8 bf2 = *(const short8*)(kWT + (size_t)(dt * 16 + l15) * 256 + es * 32 + quad * 8);
            c2 = __builtin_amdgcn_mfma_f32_16x16x32_bf16(af2[es], bf2, c2, 0, 0, 0);
        }
        #pragma unroll
        for (int r = 0; r < 4; r++)
            qkl[(quad * 4 + r) * 264 + dt * 16 + l15] = f2bf(c2[r]);
    }
    __syncthreads();

    // ---- qkf: re-read qkl rows in A-frag order; wave w stores ds = w*2, w*2+1 ----
    #pragma unroll
    for (int i = 0; i < 2; i++) {
        int ds = w * 2 + i;
        short8 v = *(const short8*)(&qkl[l15 * 264 + ds * 32 + quad * 8]);
        *(short8*)(qkf + (size_t)(b * 8 + ds) * 512 + lane * 8) = v;
    }
}

// ---------------- THE hot kernel: dist = qk@x^T (+qkb) -> softmax -> ax = attn@x -----
// grid = B*16; 4 waves. dist consumes the prefetch registers pf directly (identical
// values to the rows this wave stages); xt is only needed by ax -> 2 barriers/sub.
__launch_bounds__(256, 4)
__global__ void katt(const ushort* __restrict__ xgs, const ushort* __restrict__ qkf,
                     const float* __restrict__ qkb, float* __restrict__ denom,
                     float* __restrict__ partials) {
    int b = blockIdx.x >> 4, chunk = blockIdx.x & 15;
    int tid = threadIdx.x;
    int lane = tid & 63, w = tid >> 6;
    int l15 = lane & 15, quad = lane >> 4;

    __shared__ ushort xt[64 * 268];     // sub-tile x [n_local][d], pitch 268 (34.3 KB)
    __shared__ ushort attn[16 * 72];    // attn [s][n_local], pitch 72

    short8 qkfr[8];
    #pragma unroll
    for (int ds = 0; ds < 8; ds++)
        qkfr[ds] = *(const short8*)(qkf + ((size_t)(b * 8 + ds) * 512 + lane * 8));
    float4 qo = *(const float4*)(qkb + b * 16 + quad * 4);

    f32x4 pacc[4];
    #pragma unroll
    for (int u = 0; u < 4; u++) pacc[u] = f32x4{0.f, 0.f, 0.f, 0.f};
    float dp0 = 0.f, dp1 = 0.f, dp2 = 0.f, dp3 = 0.f;

    int tile0 = b * 256 + chunk * 16;

    short8 pf[8];
    #pragma unroll
    for (int i = 0; i < 8; i++)
        pf[i] = *(const short8*)(xgs + (((size_t)(tile0 + w) * 8 + i) * 64 + lane) * 8);

    #pragma unroll 1
    for (int sub = 0; sub < 4; sub++) {
        __syncthreads();                // prior ax done reading xt/attn
        #pragma unroll
        for (int i = 0; i < 8; i++)
            *(short8*)(&xt[(w * 16 + l15) * 268 + i * 32 + quad * 8]) = pf[i];
        // ===== dist from pf (== this wave's staged rows) =====
        f32x4 dc = f32x4{0.f, 0.f, 0.f, 0.f};
        #pragma unroll
        for (int ds = 0; ds < 8; ds++)
            dc = __builtin_amdgcn_mfma_f32_16x16x32_bf16(qkfr[ds], pf[ds], dc, 0, 0, 0);
        dc[0] += qo.x; dc[1] += qo.y; dc[2] += qo.z; dc[3] += qo.w;
        float mx = fmaxf(fmaxf(dc[0], dc[1]), fmaxf(dc[2], dc[3]));
        mx = fmaxf(mx, __shfl_xor(mx, 16));
        mx = fmaxf(mx, __shfl_xor(mx, 32));
        float e0 = __expf(dc[0] - mx), e1 = __expf(dc[1] - mx);
        float e2 = __expf(dc[2] - mx), e3 = __expf(dc[3] - mx);
        float lsum = e0 + e1 + e2 + e3;
        lsum += __shfl_xor(lsum, 16); lsum += __shfl_xor(lsum, 32);
        float inv = 1.f / lsum;
        float p0 = e0 * inv, p1 = e1 * inv, p2 = e2 * inv, p3 = e3 * inv;
        dp0 += p0; dp1 += p1; dp2 += p2; dp3 += p3;
        attn[(quad * 4 + 0) * 72 + w * 16 + l15] = f2bf(p0);
        attn[(quad * 4 + 1) * 72 + w * 16 + l15] = f2bf(p1);
        attn[(quad * 4 + 2) * 72 + w * 16 + l15] = f2bf(p2);
        attn[(quad * 4 + 3) * 72 + w * 16 + l15] = f2bf(p3);
        if (sub < 3) {                  // pf dead after dist -> prefetch next
            #pragma unroll
            for (int i = 0; i < 8; i++)
                pf[i] = *(const short8*)(xgs + (((size_t)(tile0 + (sub + 1) * 4 + w) * 8 + i) * 64 + lane) * 8);
        }
        __syncthreads();                // xt + attn visible to all waves

        // ===== ax: pacc[s][d] += sum_n attn[s,n]*x[n,d]; wave w owns d [w*64,(w+1)*64) =====
        #pragma unroll
        for (int ns = 0; ns < 2; ns++) {
            short8 aa = *(const short8*)(&attn[l15 * 72 + ns * 32 + quad * 8]);
            #pragma unroll
            for (int u = 0; u < 4; u++) {
                ushort tmp[8];
                #pragma unroll
                for (int j = 0; j < 8; j++)
                    tmp[j] = xt[(ns * 32 + quad * 8 + j) * 268 + (w * 4 + u) * 16 + l15];
                pacc[u] = __builtin_amdgcn_mfma_f32_16x16x32_bf16(aa, *(short8*)tmp, pacc[u], 0, 0, 0);
            }
        }
    }

    #pragma unroll
    for (int m = 1; m < 16; m <<= 1) {
        dp0 += __shfl_xor(dp0, m); dp1 += __shfl_xor(dp1, m);
        dp2 += __shfl_xor(dp2, m); dp3 += __shfl_xor(dp3, m);
    }
    if (l15 == 0) {
        atomicAdd(&denom[b * 16 + quad * 4 + 0], dp0);
        atomicAdd(&denom[b * 16 + quad * 4 + 1], dp1);
        atomicAdd(&denom[b * 16 + quad * 4 + 2], dp2);
        atomicAdd(&denom[b * 16 + quad * 4 + 3], dp3);
    }

    float* pout = partials + (size_t)(b * 16 + chunk) * 4096;   // [s][d]
    #pragma unroll
    for (int u = 0; u < 4; u++)
        #pragma unroll
        for (int r = 0; r < 4; r++)
            pout[(quad * 4 + r) * 256 + (w * 4 + u) * 16 + l15] = pacc[u][r];
}

// ---------------- reduce chunks + apply vW^T + vb, divide by denom -------------------
__global__ void kred2(const float* __restrict__ partials, const float* __restrict__ denom,
                      const ushort* __restrict__ vWT, const float* __restrict__ vb,
                      float* __restrict__ slots) {
    int b = blockIdx.x >> 2, dq = blockIdx.x & 3, t = threadIdx.x;
    __shared__ float axs[4096];
    __shared__ float dn[16];
    #pragma unroll
    for (int i = 0; i < 16; i++) {
        int idx = i * 256 + t;
        float ssum = 0.f;
        #pragma unroll
        for (int c = 0; c < 16; c++) ssum += partials[(size_t)b * 65536 + c * 4096 + idx];
        axs[idx] = ssum;
    }
    if (t < 16) dn[t] = denom[b * 16 + t];
    __syncthreads();
    int d = dq * 64 + (t & 63), sg = t >> 6;
    float acc[4];
    #pragma unroll
    for (int i = 0; i < 4; i++) acc[i] = 0.f;
    for (int e = 0; e < 256; e++) {
        float wv = bf2f(vWT[e * 256 + d]);
        #pragma unroll
        for (int i = 0; i < 4; i++) acc[i] += axs[(sg + i * 4) * 256 + e] * wv;
    }
    float vbd = vb[d];
    #pragma unroll
    for (int i = 0; i < 4; i++) {
        int s = sg + i * 4;
        float A = dn[s];
        slots[b * 4096 + s * 256 + d] = (acc[i] + vbd * A) / (A + 1e-7f);
    }
}

// ---------------- LN2 + MLP layer 1 (relu) -> htmp bf16 ------------------------------
__global__ void kfin1(const float* __restrict__ slots_in, const float* __restrict__ ln2w,
                      const float* __restrict__ ln2b, const ushort* __restrict__ m1WT,
                      const float* __restrict__ m1b, ushort* __restrict__ htmp) {
    int b = blockIdx.x >> 2, hq = blockIdx.x & 3, t = threadIdx.x;
    __shared__ float s2[4096];
    __shared__ float r1[256], r2[256];
    const float* sp = slots_in + b * 4096;
    float vals[16]; float s = 0.f, sq = 0.f;
    #pragma unroll
    for (int k = 0; k < 16; k++) { float v = sp[k * 256 + t]; vals[k] = v; s += v; sq += v * v; }
    r1[t] = s; r2[t] = sq; __syncthreads();
    for (int st = 128; st > 0; st >>= 1) {
        if (t < st) { r1[t] += r1[t + st]; r2[t] += r2[t + st]; }
        __syncthreads();
    }
    float m  = r1[0] * (1.f / 4096.f);
    float rs = rsqrtf(r2[0] * (1.f / 4096.f) - m * m + LN_EPS);
    #pragma unroll
    for (int k = 0; k < 16; k++)
        s2[k * 256 + t] = (vals[k] - m) * rs * ln2w[k * 256 + t] + ln2b[k * 256 + t];
    __syncthreads();
    int j = hq * 128 + (t & 127), sg2 = t >> 7;
    float acc[8];
    #pragma unroll
    for (int i = 0; i < 8; i++) acc[i] = 0.f;
    for (int d = 0; d < 256; d++) {
        float wv = bf2f(m1WT[d * 512 + j]);
        #pragma unroll
        for (int i = 0; i < 8; i++) acc[i] += s2[(sg2 + i * 2) * 256 + d] * wv;
    }
    float bias = m1b[j];
    #pragma unroll
    for (int i = 0; i < 8; i++)
        htmp[b * 8192 + (sg2 + i * 2) * 512 + j] = f2bf(fmaxf(acc[i] + bias, 0.f));
}

// ---------------- MLP layer 2 + residual ---------------------------------------------
__global__ void kfin2(const ushort* __restrict__ htmp, const ushort* __restrict__ m2WT,
                      const float* __restrict__ m2b, float* __restrict__ slots,
                      float* __restrict__ final_out, int write_final) {
    int b = blockIdx.x >> 2, dq = blockIdx.x & 3, t = threadIdx.x;
    __shared__ float hl[8192];
    #pragma unroll
    for (int i = 0; i < 32; i++) {
        int idx = i * 256 + t;
        hl[idx] = bf2f(htmp[b * 8192 + idx]);
    }
    __syncthreads();
    int d = dq * 64 + (t & 63), sg = t >> 6;
    float acc[4];
    #pragma unroll
    for (int i = 0; i < 4; i++) acc[i] = 0.f;
    for (int j = 0; j < 512; j++) {
        float wv = bf2f(m2WT[j * 256 + d]);
        #pragma unroll
        for (int i = 0; i < 4; i++) acc[i] += hl[(sg + i * 4) * 512 + j] * wv;
    }
    float bias2 = m2b[d];
    #pragma unroll
    for (int i = 0; i < 4; i++) {
        int s = sg + i * 4;
        float raw = slots[b * 4096 + s * 256 + d];
        float val = raw + acc[i] + bias2;
        slots[b * 4096 + s * 256 + d] = val;
        if (write_final) final_out[b * 4096 + s * 256 + d] = val;
    }
}

extern "C" void kernel_launch(void* const* d_in, const int* in_sizes, int n_in,
                              void* d_out, int out_size, void* d_ws, size_t ws_size,
                              hipStream_t stream) {
    const float* inputs     = (const float*)d_in[0];
    const float* slots_init = (const float*)d_in[1];
    const float* mu         = (const float*)d_in[2];
    const float* logsig     = (const float*)d_in[3];
    const float* ln0w       = (const float*)d_in[4];
    const float* ln0b       = (const float*)d_in[5];
    const float* ln1w       = (const float*)d_in[6];
    const float* ln1b       = (const float*)d_in[7];
    const float* ln2w       = (const float*)d_in[8];
    const float* ln2b       = (const float*)d_in[9];
    const float* qW         = (const float*)d_in[10];
    const float* qb         = (const float*)d_in[11];
    const float* kW         = (const float*)d_in[12];
    const float* kb         = (const float*)d_in[13];
    const float* vW         = (const float*)d_in[14];
    const float* vb         = (const float*)d_in[15];
    const float* m1W        = (const float*)d_in[16];
    const float* m1b        = (const float*)d_in[17];
    const float* m2W        = (const float*)d_in[18];
    const float* m2b        = (const float*)d_in[19];

    char* ws = (char*)d_ws;
    ushort* xgs     = (ushort*)(ws);                   // 134,217,728 B
    float*  partials= (float*)(ws + 134217728);        //  16,777,216 B
    ushort* qkf     = (ushort*)(ws + 150994944);       //     524,288 B
    ushort* htmp    = (ushort*)(ws + 151519232);       //   1,048,576 B
    float*  slots   = (float*)(ws + 152567808);        //   1,048,576 B
    ushort* qWc     = (ushort*)(ws + 153616384);       //     393,216 B
    ushort* m1WT    = (ushort*)(ws + 154009600);       //     786,432 B
    ushort* m2WT    = (ushort*)(ws + 154796032);       //     786,432 B
    ushort* vWT     = (ushort*)(ws + 155582464);       //     393,216 B
    float*  denom   = (float*)(ws + 155975680);        //       4,096 B
    float*  qkb     = (float*)(ws + 155979776);        //       4,096 B
    float*  sums    = (float*)(ws + 155983872);        //         512 B (pad to 155,984,384)
    ushort* kWT     = (ushort*)(ws + 155984384);       //     393,216 B
    // total 156,377,600 B <= 157,295,104 B proven available

    kinit<<<1024, 256, 0, stream>>>(slots_init, mu, logsig, slots, sums);
    ktrans<<<336, 256, 0, stream>>>(qW, kW, m1W, m2W, vW, qWc, kWT, m1WT, m2WT, vWT);
    l0a<<<2048, 256, 0, stream>>>(inputs, sums);
    l0bs<<<1024, 256, 0, stream>>>(inputs, ln0w, ln0b, sums, xgs);

    for (int it = 0; it < 3; it++) {
        kqm<<<64, 256, 0, stream>>>(slots, ln1w, ln1b, qWc + it * 65536, qb + it * 256,
                                    kWT + it * 65536, kb + it * 256, qkf, qkb, denom);
        katt<<<1024, 256, 0, stream>>>(xgs, qkf, qkb, denom, partials);
        kred2<<<256, 256, 0, stream>>>(partials, denom, vWT + it * 65536, vb + it * 256, slots);
        kfin1<<<256, 256, 0, stream>>>(slots, ln2w, ln2b, m1WT + it * 131072, m1b + it * 512, htmp);
        kfin2<<<256, 256, 0, stream>>>(htmp, m2WT + it * 131072, m2b + it * 256, slots,
                                       (float*)d_out, it == 2 ? 1 : 0);
    }
}